// Round 1
// baseline (179.073 us; speedup 1.0000x reference)
//
#include <hip/hip_runtime.h>
#include <hip/hip_bf16.h>

#define FLOAT_EPS 1.1920928955078125e-07f

typedef float f32x4 __attribute__((ext_vector_type(4)));
typedef short s16x8 __attribute__((ext_vector_type(8)));

#define B_ 16
#define P_ 8192
#define I_ 256
#define O_ 128
#define L_ 256
#define IO_ (I_*O_)   // 32768

__device__ __forceinline__ float clip01(float v) {
    return fminf(fmaxf(v, 0.0f), 1.0f);
}

// ---------------- K0: transpose latent [16][256] -> latT [256][16] ----------------
__global__ void rl_k0_lat(const float* __restrict__ lat, float* __restrict__ latT) {
    for (int e = threadIdx.x; e < B_ * L_; e += blockDim.x) {
        int b = e & 15, l = e >> 4;
        latT[l * 16 + b] = lat[b * L_ + l];
    }
}

// ---------------- K1: logits[ks][b][i][o] = sum_l latT[l][b]*comp_ks[l][i][o] ------
// grid (256, 2), block 128. n = i*O+o column index; each thread owns one n, 16 b-accs.
__global__ __launch_bounds__(128) void rl_k1_logits(
        const float* __restrict__ latT,
        const float* __restrict__ c1, const float* __restrict__ c2,
        float* __restrict__ lg) {
    const int n  = blockIdx.x * 128 + threadIdx.x;
    const int ks = blockIdx.y;
    const float* __restrict__ C = ks ? c2 : c1;

    float acc[16];
#pragma unroll
    for (int b = 0; b < 16; ++b) acc[b] = 0.0f;

#pragma unroll 4
    for (int l = 0; l < L_; ++l) {
        float cv = C[(size_t)l * IO_ + n];
        const float4* lt = (const float4*)(latT + l * 16);
        float4 t0 = lt[0], t1 = lt[1], t2 = lt[2], t3 = lt[3];
        acc[0]  += t0.x * cv; acc[1]  += t0.y * cv; acc[2]  += t0.z * cv; acc[3]  += t0.w * cv;
        acc[4]  += t1.x * cv; acc[5]  += t1.y * cv; acc[6]  += t1.z * cv; acc[7]  += t1.w * cv;
        acc[8]  += t2.x * cv; acc[9]  += t2.y * cv; acc[10] += t2.z * cv; acc[11] += t2.w * cv;
        acc[12] += t3.x * cv; acc[13] += t3.y * cv; acc[14] += t3.z * cv; acc[15] += t3.w * cv;
    }
#pragma unroll
    for (int b = 0; b < 16; ++b) lg[(size_t)(ks * 16 + b) * IO_ + n] = acc[b];
}

// ---------------- K2: double softmax over i, write M_T[b][n][i] bf16 ----------------
// grid (2, 2, 16) = (o-tile, ks, b), block 256 = 4 waves; lane dim = o (coalesced),
// 4 i-quarters per column reduced via LDS.
__global__ __launch_bounds__(256) void rl_k2_mask(
        const float* __restrict__ logits, const float* __restrict__ u,
        const float* __restrict__ temp_p, __hip_bfloat16* __restrict__ MT) {
    const int oo = threadIdx.x & 63;
    const int q  = threadIdx.x >> 6;
    const int o0 = blockIdx.x * 64;
    const int ks = blockIdx.y;
    const int b  = blockIdx.z;

    __shared__ float slab[I_][64];
    __shared__ float red[4][64];

    const float* __restrict__ z  = logits + (size_t)(ks * 16 + b) * IO_ + o0 + oo;
    const float* __restrict__ up = u + (size_t)(b * 2 + ks) * IO_ + o0 + oo;

    float T = temp_p[0];
    T = fminf(fmaxf(T, FLOAT_EPS), 2.0f);
    T = fmaxf(T, 0.001f);
    const float rT = 1.0f / T;

    const int i0 = q * 64, i1 = q * 64 + 64;

    // pass 1: max over i of logits column
    float m = -INFINITY;
    for (int i = i0; i < i1; ++i) m = fmaxf(m, z[(size_t)i * O_]);
    red[q][oo] = m; __syncthreads();
    m = fmaxf(fmaxf(red[0][oo], red[1][oo]), fmaxf(red[2][oo], red[3][oo]));
    __syncthreads();

    // pass 2: sum exp
    float S = 0.0f;
    for (int i = i0; i < i1; ++i) S += expf(z[(size_t)i * O_] - m);
    red[q][oo] = S; __syncthreads();
    S = (red[0][oo] + red[1][oo]) + (red[2][oo] + red[3][oo]);
    __syncthreads();
    const float invS = 1.0f / S;

    // pass 3: s_i = (log(p_i + eps) + g_i)/T ; track max
    float m2 = -INFINITY;
    for (int i = i0; i < i1; ++i) {
        float p  = expf(z[(size_t)i * O_] - m) * invS;
        float uu = fmaxf(up[(size_t)i * O_], FLOAT_EPS);
        float g  = -logf(-logf(uu));
        float s  = (logf(p + FLOAT_EPS) + g) * rT;
        slab[i][oo] = s;
        m2 = fmaxf(m2, s);
    }
    red[q][oo] = m2; __syncthreads();
    m2 = fmaxf(fmaxf(red[0][oo], red[1][oo]), fmaxf(red[2][oo], red[3][oo]));
    __syncthreads();

    // pass 4: sum exp of s
    float S2 = 0.0f;
    for (int i = i0; i < i1; ++i) S2 += expf(slab[i][oo] - m2);
    red[q][oo] = S2; __syncthreads();
    S2 = (red[0][oo] + red[1][oo]) + (red[2][oo] + red[3][oo]);
    const float invS2 = 1.0f / S2;

    // pass 5: write mask_s as bf16 into M_T[b][n = ks*128 + o][i]
    __hip_bfloat16* __restrict__ row = MT + ((size_t)(b * 256 + ks * 128 + o0 + oo)) * I_;
    for (int i = i0; i < i1; i += 2) {
        float v0 = expf(slab[i][oo]     - m2) * invS2;
        float v1 = expf(slab[i + 1][oo] - m2) * invS2;
        __hip_bfloat162 pk = __float22bfloat162_rn(make_float2(v0, v1));
        *(__hip_bfloat162*)(row + i) = pk;
    }
}

// ---------------- K3: C[p][n] = sum_i x[b][p][i] * M_T[b][n][i], fused epilogue -----
// grid (64, 16) = (row-tile, b), block 256 = 4 waves. BM=128, BN=256(full), BK=64.
// Per wave: 32 rows x 256 cols -> acc[2][16] f32x4. XOR-swizzled LDS (row&7)<<4.
__global__ __launch_bounds__(256) void rl_k3_gemm(
        const float* __restrict__ X, const __hip_bfloat16* __restrict__ MT,
        float* __restrict__ OUT) {
    const int tid  = threadIdx.x;
    const int lane = tid & 63, wid = tid >> 6;
    const int b    = blockIdx.y;
    const int row0 = blockIdx.x * 128;

    __shared__ short Alds[128 * 64];   // [row][k] bf16, swizzled
    __shared__ short Blds[256 * 64];   // [n][k]  bf16, swizzled

    const float* __restrict__ Xb            = X   + (size_t)b * P_ * I_;
    const __hip_bfloat16* __restrict__ MTb  = MT  + (size_t)b * 256 * 256;
    float* __restrict__ Ob                  = OUT + (size_t)b * P_ * 512;

    f32x4 acc[2][16];
#pragma unroll
    for (int i = 0; i < 2; ++i)
#pragma unroll
        for (int j = 0; j < 16; ++j) acc[i][j] = (f32x4){0.f, 0.f, 0.f, 0.f};

    const int rA = tid >> 3, cA = tid & 7;

    for (int k0 = 0; k0 < 256; k0 += 64) {
        __syncthreads();
        // stage A: 128 rows x 64 k, fp32 -> bf16
#pragma unroll
        for (int rr = 0; rr < 4; ++rr) {
            int row = rr * 32 + rA;
            const float* src = Xb + (size_t)(row0 + row) * I_ + k0 + cA * 8;
            float4 f0 = *(const float4*)src;
            float4 f1 = *(const float4*)(src + 4);
            union { s16x8 v; __hip_bfloat162 h[4]; } cv;
            cv.h[0] = __float22bfloat162_rn(make_float2(f0.x, f0.y));
            cv.h[1] = __float22bfloat162_rn(make_float2(f0.z, f0.w));
            cv.h[2] = __float22bfloat162_rn(make_float2(f1.x, f1.y));
            cv.h[3] = __float22bfloat162_rn(make_float2(f1.z, f1.w));
            int off = row * 128 + ((cA * 16) ^ ((row & 7) << 4));
            *(s16x8*)((char*)Alds + off) = cv.v;
        }
        // stage B: 256 n x 64 k bf16 (L2-resident, 32 KB)
#pragma unroll
        for (int it = 0; it < 8; ++it) {
            int idx = it * 256 + tid;
            int rB = idx >> 3, cB = idx & 7;
            s16x8 v = *(const s16x8*)(MTb + rB * 256 + k0 + cB * 8);
            int off = rB * 128 + ((cB * 16) ^ ((rB & 7) << 4));
            *(s16x8*)((char*)Blds + off) = v;
        }
        __syncthreads();
        // MFMA: 16x16x32 bf16
#pragma unroll
        for (int kk = 0; kk < 2; ++kk) {
            const int kb2 = (kk * 32 + ((lane >> 4) * 8)) * 2;  // byte offset in row
            s16x8 af[2];
#pragma unroll
            for (int fm = 0; fm < 2; ++fm) {
                int row = wid * 32 + fm * 16 + (lane & 15);
                af[fm] = *(s16x8*)((char*)Alds + row * 128 + (kb2 ^ ((row & 7) << 4)));
            }
#pragma unroll
            for (int fn = 0; fn < 16; ++fn) {
                int n = fn * 16 + (lane & 15);
                s16x8 bf = *(s16x8*)((char*)Blds + n * 128 + (kb2 ^ ((n & 7) << 4)));
                acc[0][fn] = __builtin_amdgcn_mfma_f32_16x16x32_bf16(af[0], bf, acc[0][fn], 0, 0, 0);
                acc[1][fn] = __builtin_amdgcn_mfma_f32_16x16x32_bf16(af[1], bf, acc[1][fn], 0, 0, 0);
            }
        }
    }

    // epilogue: a = cols [0,128), b = cols [128,256); write 4 clipped segments
    const int cb = lane & 15;
    const int rb = (lane >> 4) * 4;
#pragma unroll
    for (int fm = 0; fm < 2; ++fm) {
#pragma unroll
        for (int fn = 0; fn < 8; ++fn) {
#pragma unroll
            for (int r = 0; r < 4; ++r) {
                int p = row0 + wid * 32 + fm * 16 + rb + r;
                float a  = acc[fm][fn][r];
                float bb = acc[fm][fn + 8][r];
                float* op = Ob + (size_t)p * 512 + fn * 16 + cb;
                op[0]   = clip01(a + bb);
                op[128] = clip01(a + bb - 1.0f);
                op[256] = clip01(a - bb);
                op[384] = clip01(bb - a);
            }
        }
    }
}

extern "C" void kernel_launch(void* const* d_in, const int* in_sizes, int n_in,
                              void* d_out, int out_size, void* d_ws, size_t ws_size,
                              hipStream_t stream) {
    const float* x    = (const float*)d_in[0];
    const float* lat  = (const float*)d_in[1];
    const float* c1   = (const float*)d_in[2];
    const float* c2   = (const float*)d_in[3];
    const float* temp = (const float*)d_in[4];
    const float* u    = (const float*)d_in[5];
    float* out = (float*)d_out;

    char* ws = (char*)d_ws;
    float*          logits = (float*)ws;                         // 2*16*32768 f32 = 4 MB
    __hip_bfloat16* MT     = (__hip_bfloat16*)(ws + (4 << 20));  // 16*256*256 bf16 = 2 MB
    float*          latT   = (float*)(ws + (6 << 20));           // 16 KB

    rl_k0_lat   <<<1, 256, 0, stream>>>(lat, latT);
    rl_k1_logits<<<dim3(256, 2), 128, 0, stream>>>(latT, c1, c2, logits);
    rl_k2_mask  <<<dim3(2, 2, 16), 256, 0, stream>>>(logits, u, temp, MT);
    rl_k3_gemm  <<<dim3(64, 16), 256, 0, stream>>>(x, MT, out);
}

// Round 2
// 147.867 us; speedup vs baseline: 1.2110x; 1.2110x over previous
//
#include <hip/hip_runtime.h>
#include <hip/hip_bf16.h>

#define FLOAT_EPS 1.1920928955078125e-07f

typedef float f32x4 __attribute__((ext_vector_type(4)));
typedef short s16x8 __attribute__((ext_vector_type(8)));

#define B_ 16
#define P_ 8192
#define I_ 256
#define O_ 128
#define L_ 256
#define IO_ (I_*O_)   // 32768

__device__ __forceinline__ float clip01(float v) {
    return fminf(fmaxf(v, 0.0f), 1.0f);
}

// ---------------- K0: transpose latent [16][256] -> latT [256][16] ----------------
__global__ void rl_k0_lat(const float* __restrict__ lat, float* __restrict__ latT) {
    for (int e = threadIdx.x; e < B_ * L_; e += blockDim.x) {
        int b = e >> 8, l = e & 255;     // linear over lat (coalesced read)
        latT[l * 16 + b] = lat[e];
    }
}

// ---------------- K1: partial logits, l split 2-way for occupancy ----------------
// grid (128, 2, 2) = (n-block, ks, l-half), block 256.
// lgP[(lh*32 + ks*16 + b)*IO + n] = sum_{l in half} latT[l][b]*C[l][n]
__global__ __launch_bounds__(256) void rl_k1_logits(
        const float* __restrict__ latT,
        const float* __restrict__ c1, const float* __restrict__ c2,
        float* __restrict__ lgP) {
    const int n  = blockIdx.x * 256 + threadIdx.x;
    const int ks = blockIdx.y;
    const int lh = blockIdx.z;
    const float* __restrict__ C  = (ks ? c2 : c1) + (size_t)lh * 128 * IO_;
    const float* __restrict__ LT = latT + lh * 128 * 16;

    float acc[16];
#pragma unroll
    for (int b = 0; b < 16; ++b) acc[b] = 0.0f;

#pragma unroll 8
    for (int l = 0; l < 128; ++l) {
        float cv = C[(size_t)l * IO_ + n];
        const float4* lt = (const float4*)(LT + l * 16);   // uniform -> s_load
        float4 t0 = lt[0], t1 = lt[1], t2 = lt[2], t3 = lt[3];
        acc[0]  += t0.x * cv; acc[1]  += t0.y * cv; acc[2]  += t0.z * cv; acc[3]  += t0.w * cv;
        acc[4]  += t1.x * cv; acc[5]  += t1.y * cv; acc[6]  += t1.z * cv; acc[7]  += t1.w * cv;
        acc[8]  += t2.x * cv; acc[9]  += t2.y * cv; acc[10] += t2.z * cv; acc[11] += t2.w * cv;
        acc[12] += t3.x * cv; acc[13] += t3.y * cv; acc[14] += t3.z * cv; acc[15] += t3.w * cv;
    }
    float* o = lgP + ((size_t)(lh * 32 + ks * 16)) * IO_ + n;
#pragma unroll
    for (int b = 0; b < 16; ++b) o[(size_t)b * IO_] = acc[b];
}

// ---------------- K2: double softmax over i, write M_T[b][n][i] bf16 ----------------
// grid (8, 2, 16) = (o-tile16, ks, b), block 256 = 16 i-groups x 16 o-lanes.
__global__ __launch_bounds__(256) void rl_k2_mask(
        const float* __restrict__ lgP, const float* __restrict__ u,
        const float* __restrict__ temp_p, __hip_bfloat16* __restrict__ MT) {
    const int oo = threadIdx.x & 15;
    const int g  = threadIdx.x >> 4;     // 16 groups, 16 i's each
    const int o0 = blockIdx.x * 16;
    const int ks = blockIdx.y;
    const int b  = blockIdx.z;

    __shared__ float slab[I_][16];
    __shared__ float red[16][16];

    const float* __restrict__ z0 = lgP + (size_t)(ks * 16 + b) * IO_ + o0 + oo;
    const float* __restrict__ z1 = z0 + (size_t)32 * IO_;
    const float* __restrict__ up = u + ((size_t)b * 2 + ks) * IO_ + o0 + oo;

    float T = temp_p[0];
    T = fminf(fmaxf(T, FLOAT_EPS), 2.0f);
    T = fmaxf(T, 0.001f);
    const float rT = 1.0f / T;

    const int i0 = g * 16, i1 = i0 + 16;

    // pass 0: combine partial logits into LDS column
    for (int i = i0; i < i1; ++i)
        slab[i][oo] = z0[(size_t)i * O_] + z1[(size_t)i * O_];
    __syncthreads();

    // pass 1: max over i
    float m = -INFINITY;
    for (int i = i0; i < i1; ++i) m = fmaxf(m, slab[i][oo]);
    red[g][oo] = m; __syncthreads();
    m = -INFINITY;
#pragma unroll
    for (int j = 0; j < 16; ++j) m = fmaxf(m, red[j][oo]);
    __syncthreads();

    // pass 2: sum exp
    float S = 0.0f;
    for (int i = i0; i < i1; ++i) S += expf(slab[i][oo] - m);
    red[g][oo] = S; __syncthreads();
    S = 0.0f;
#pragma unroll
    for (int j = 0; j < 16; ++j) S += red[j][oo];
    __syncthreads();
    const float invS = 1.0f / S;

    // pass 3: s_i = (log(p_i + eps) + g_i)/T ; overwrite slab; track max
    float m2 = -INFINITY;
    for (int i = i0; i < i1; ++i) {
        float p  = expf(slab[i][oo] - m) * invS;
        float uu = fmaxf(up[(size_t)i * O_], FLOAT_EPS);
        float gg = -logf(-logf(uu));
        float s  = (logf(p + FLOAT_EPS) + gg) * rT;
        slab[i][oo] = s;
        m2 = fmaxf(m2, s);
    }
    red[g][oo] = m2; __syncthreads();
    m2 = -INFINITY;
#pragma unroll
    for (int j = 0; j < 16; ++j) m2 = fmaxf(m2, red[j][oo]);
    __syncthreads();

    // pass 4: sum exp of s
    float S2 = 0.0f;
    for (int i = i0; i < i1; ++i) S2 += expf(slab[i][oo] - m2);
    red[g][oo] = S2; __syncthreads();
    S2 = 0.0f;
#pragma unroll
    for (int j = 0; j < 16; ++j) S2 += red[j][oo];
    const float invS2 = 1.0f / S2;

    // pass 5: write mask_s bf16 into M_T[b][n = ks*128 + o][i]
    __hip_bfloat16* __restrict__ row = MT + ((size_t)(b * 256 + ks * 128 + o0 + oo)) * I_;
    for (int i = i0; i < i1; i += 2) {
        float v0 = expf(slab[i][oo]     - m2) * invS2;
        float v1 = expf(slab[i + 1][oo] - m2) * invS2;
        __hip_bfloat162 pk = __float22bfloat162_rn(make_float2(v0, v1));
        *(__hip_bfloat162*)(row + i) = pk;
    }
}

// ---------------- K3: barrier-free streaming GEMM, B resident in LDS ----------------
// grid (16, 16) = (m-chunk of 512 rows, b), block 512 = 8 waves.
// B[b] = 256n x 256k bf16 = 128 KB LDS (XOR-swizzled). A streams global->reg frags.
__global__ __launch_bounds__(512, 2) void rl_k3_gemm(
        const float* __restrict__ X, const __hip_bfloat16* __restrict__ MT,
        float* __restrict__ OUT) {
    const int tid  = threadIdx.x;
    const int lane = tid & 63, wid = tid >> 6;
    const int b    = blockIdx.y;

    __shared__ short Blds[256 * 256];   // 128 KB

    const float* __restrict__ Xb           = X   + (size_t)b * P_ * I_;
    const __hip_bfloat16* __restrict__ MTb = MT  + (size_t)b * 65536;
    float* __restrict__ Ob                 = OUT + (size_t)b * P_ * 512;

    // load B once, swizzled: byte ^= (n&7)<<4
#pragma unroll
    for (int it = 0; it < 16; ++it) {
        int idx = it * 512 + tid;          // 0..8191 chunks of 8 bf16
        int n = idx >> 5, c = idx & 31;
        s16x8 v = *(const s16x8*)(MTb + n * 256 + c * 8);
        *(s16x8*)((char*)Blds + n * 512 + ((c * 16) ^ ((n & 7) << 4))) = v;
    }
    __syncthreads();

    const int l15 = lane & 15, lhi = lane >> 4;

    for (int itm = 0; itm < 2; ++itm) {
        const int rowb = blockIdx.x * 512 + itm * 256 + wid * 32 + l15;
        const float* __restrict__ A0 = Xb + (size_t)rowb * I_ + lhi * 8;

        // preload + convert all A fragments for this 32-row group
        s16x8 af[2][8];
#pragma unroll
        for (int fm = 0; fm < 2; ++fm)
#pragma unroll
        for (int kk = 0; kk < 8; ++kk) {
            const float* src = A0 + fm * 16 * I_ + kk * 32;
            float4 f0 = *(const float4*)src;
            float4 f1 = *(const float4*)(src + 4);
            union { s16x8 v; __hip_bfloat162 h[4]; } cv;
            cv.h[0] = __float22bfloat162_rn(make_float2(f0.x, f0.y));
            cv.h[1] = __float22bfloat162_rn(make_float2(f0.z, f0.w));
            cv.h[2] = __float22bfloat162_rn(make_float2(f1.x, f1.y));
            cv.h[3] = __float22bfloat162_rn(make_float2(f1.z, f1.w));
            af[fm][kk] = cv.v;
        }

        f32x4 acc[2][16];
#pragma unroll
        for (int i = 0; i < 2; ++i)
#pragma unroll
        for (int j = 0; j < 16; ++j) acc[i][j] = (f32x4){0.f, 0.f, 0.f, 0.f};

#pragma unroll
        for (int kk = 0; kk < 8; ++kk) {
            const int kb = kk * 64 + lhi * 16;   // byte offset in B row
#pragma unroll
            for (int fn = 0; fn < 16; ++fn) {
                int n = fn * 16 + l15;
                s16x8 bf = *(const s16x8*)((const char*)Blds + n * 512 + (kb ^ ((n & 7) << 4)));
                acc[0][fn] = __builtin_amdgcn_mfma_f32_16x16x32_bf16(af[0][kk], bf, acc[0][fn], 0, 0, 0);
                acc[1][fn] = __builtin_amdgcn_mfma_f32_16x16x32_bf16(af[1][kk], bf, acc[1][fn], 0, 0, 0);
            }
        }

        // epilogue: a = cols [0,128), b = cols [128,256)
        const int cb = l15, rb = lhi * 4;
#pragma unroll
        for (int fm = 0; fm < 2; ++fm)
#pragma unroll
        for (int fn = 0; fn < 8; ++fn)
#pragma unroll
        for (int r = 0; r < 4; ++r) {
            int p = blockIdx.x * 512 + itm * 256 + wid * 32 + fm * 16 + rb + r;
            float a  = acc[fm][fn][r];
            float bb = acc[fm][fn + 8][r];
            float* op = Ob + (size_t)p * 512 + fn * 16 + cb;
            op[0]   = clip01(a + bb);
            op[128] = clip01(a + bb - 1.0f);
            op[256] = clip01(a - bb);
            op[384] = clip01(bb - a);
        }
    }
}

extern "C" void kernel_launch(void* const* d_in, const int* in_sizes, int n_in,
                              void* d_out, int out_size, void* d_ws, size_t ws_size,
                              hipStream_t stream) {
    const float* x    = (const float*)d_in[0];
    const float* lat  = (const float*)d_in[1];
    const float* c1   = (const float*)d_in[2];
    const float* c2   = (const float*)d_in[3];
    const float* temp = (const float*)d_in[4];
    const float* u    = (const float*)d_in[5];
    float* out = (float*)d_out;

    char* ws = (char*)d_ws;
    float*          lgP  = (float*)ws;                          // 2 halves * 4 MB = 8 MB
    __hip_bfloat16* MT   = (__hip_bfloat16*)(ws + (8 << 20));   // 2 MB
    float*          latT = (float*)(ws + (10 << 20));           // 16 KB

    rl_k0_lat   <<<1, 256, 0, stream>>>(lat, latT);
    rl_k1_logits<<<dim3(128, 2, 2), 256, 0, stream>>>(latT, c1, c2, lgP);
    rl_k2_mask  <<<dim3(8, 2, 16), 256, 0, stream>>>(lgP, u, temp, MT);
    rl_k3_gemm  <<<dim3(16, 16), 512, 0, stream>>>(x, MT, out);
}